// Round 6
// baseline (89.189 us; speedup 1.0000x reference)
//
#include <hip/hip_runtime.h>
#include <math.h>

#define NROI 2000
#define NCLS 21
#define NFG  20
#define NPAD 2048
#define NTOT (NFG * NROI)

// ---- workspace layout (bytes) ----
#define OFF_SIDX    0u          // int    [NFG*NPAD]            163840
#define OFF_SPROB   163840u     // float  [NFG*NPAD]            163840
#define OFF_SBOX    327680u     // float4 [NFG*NPAD]            655360
#define OFF_VC      983040u     // int    [NFG] (padded)           256
#define OFF_MASK    983296u     // u64    [NFG*NPAD*32]       10485760
// total ~11.5 MB

typedef unsigned long long u64;

// -------- kernel 1: fused decode + sort + output-prefill, one block/class ---
// Per class block: compute per-ROI softmax prob for this class (identical op
// order to the reference), pack order-preserving (key,idx) u64s, sort via
// register-resident bitonic (256 thr x 8 elems), then decode boxes for the
// sorted slots directly from rois+locs. Also prefills this class's output
// slice (zeros + labels), which is keep-independent.
#define CSW(A,B,UP) { u64 lo_ = x[A] < x[B] ? x[A] : x[B]; \
                      u64 hi_ = x[A] < x[B] ? x[B] : x[A]; \
                      x[A] = (UP) ? lo_ : hi_; x[B] = (UP) ? hi_ : lo_; }

__global__ void __launch_bounds__(256) k_sort(const float* __restrict__ rois,
                                              const float* __restrict__ locs,
                                              const float* __restrict__ scores,
                                              const float* __restrict__ scale,
                                              int* __restrict__ sidx,
                                              float* __restrict__ sprob,
                                              float4* __restrict__ sbox,
                                              int* __restrict__ Vc,
                                              float* __restrict__ out) {
#pragma clang fp contract(off)
    int c = blockIdx.x;            // fg class index 0..19
    int cc = c + 1;                // score/loc class index (skip background)
    int t = threadIdx.x;
    __shared__ u64 a[NPAD];
    __shared__ int vcount;
    if (t == 0) vcount = 0;

    // ---- build keys: softmax prob of class cc per element ----
    u64 x[8];
    int cnt = 0;
#pragma unroll
    for (int i = 0; i < 8; ++i) {
        int e = 8 * t + i;
        unsigned int u;
        if (e < NROI) {
            float s[NCLS];
            float m = -__builtin_inff();
#pragma unroll
            for (int k = 0; k < NCLS; ++k) {
                s[k] = scores[e * NCLS + k];
                m = fmaxf(m, s[k]);
            }
            float sum = 0.0f;
#pragma unroll
            for (int k = 0; k < NCLS; ++k) sum += expf(s[k] - m);
            float pr = expf(s[cc] - m) / sum;
            bool valid = pr > 0.05f;
            cnt += valid ? 1 : 0;
            float key = valid ? pr : -__builtin_inff();
            u = __float_as_uint(key);
        } else {
            u = __float_as_uint(-__builtin_inff());
        }
        u ^= (u >> 31) ? 0xFFFFFFFFu : 0x80000000u;   // order-preserving map
        x[i] = ((u64)(~u) << 32) | (unsigned int)e;   // asc == desc-prob, ties idx asc
    }
    __syncthreads();                 // vcount init visible
    if (cnt) atomicAdd(&vcount, cnt);

    // ---- prefill this class's output slice (keep-independent) ----
    {
        float4 z4 = make_float4(0.f, 0.f, 0.f, 0.f);
        float4* o5v = (float4*)out + (size_t)c * (NROI * 5 / 4);  // 10000 floats = 2500 f4
        for (int i = t; i < NROI * 5 / 4; i += 256) o5v[i] = z4;
        float lc = (float)c;
        for (int i = t; i < NROI; i += 256) {
            out[(size_t)5 * NTOT + c * NROI + i] = 0.0f;   // keep
            out[(size_t)6 * NTOT + c * NROI + i] = lc;     // labels
        }
    }

    // ---- bitonic network ----
    // k=2: up = (i&2)==0
    CSW(0,1,true)  CSW(2,3,false) CSW(4,5,true)  CSW(6,7,false)
    // k=4: up = (i&4)==0
    CSW(0,2,true)  CSW(1,3,true)  CSW(4,6,false) CSW(5,7,false)
    CSW(0,1,true)  CSW(2,3,true)  CSW(4,5,false) CSW(6,7,false)
    // k=8: up = (t&1)==0
    {
        bool up = (t & 1) == 0;
        CSW(0,4,up) CSW(1,5,up) CSW(2,6,up) CSW(3,7,up)
        CSW(0,2,up) CSW(1,3,up) CSW(4,6,up) CSW(5,7,up)
        CSW(0,1,up) CSW(2,3,up) CSW(4,5,up) CSW(6,7,up)
    }
    // k >= 16
    for (unsigned int k = 16; k <= NPAD; k <<= 1) {
        bool up = (((unsigned int)(8 * t)) & k) == 0;
        for (unsigned int j = k >> 1; j >= 8; j >>= 1) {
            if (j >= 512) {                       // cross-wave: LDS
                __syncthreads();
#pragma unroll
                for (int i = 0; i < 8; ++i) a[8 * t + i] = x[i];
                __syncthreads();
                bool lower = ((t & (j >> 3)) == 0);
                bool takeMin = (up == lower);
#pragma unroll
                for (int i = 0; i < 8; ++i) {
                    u64 y = a[(8 * t + i) ^ j];
                    u64 mn = x[i] < y ? x[i] : y;
                    u64 mx = x[i] < y ? y : x[i];
                    x[i] = takeMin ? mn : mx;
                }
            } else {                              // wave-local: shfl_xor
                int lm = (int)(j >> 3);
                bool lower = ((t & lm) == 0);
                bool takeMin = (up == lower);
#pragma unroll
                for (int i = 0; i < 8; ++i) {
                    u64 y = __shfl_xor(x[i], lm, 64);
                    u64 mn = x[i] < y ? x[i] : y;
                    u64 mx = x[i] < y ? y : x[i];
                    x[i] = takeMin ? mn : mx;
                }
            }
        }
        // j = 4,2,1 in registers
        CSW(0,4,up) CSW(1,5,up) CSW(2,6,up) CSW(3,7,up)
        CSW(0,2,up) CSW(1,3,up) CSW(4,6,up) CSW(5,7,up)
        CSW(0,1,up) CSW(2,3,up) CSW(4,5,up) CSW(6,7,up)
    }

    // ---- emit sorted slots: idx, prob (bit-exact from key), decoded box ----
    float sc = scale[0];
    float oh = 600.0f / sc, ow = 800.0f / sc;
#pragma unroll
    for (int i = 0; i < 8; ++i) {
        int slot = 8 * t + i;
        u64 p = x[i];
        int orig = (int)(p & 0xFFFFFFFFu);
        sidx[c * NPAD + slot] = orig;
        // invert the order-preserving map to recover prob bits exactly
        unsigned int m_ = ~(unsigned int)(p >> 32);
        unsigned int b_ = (m_ & 0x80000000u) ? (m_ ^ 0x80000000u) : ~m_;
        sprob[c * NPAD + slot] = __uint_as_float(b_);

        float4 bb = make_float4(0.f, 0.f, 0.f, 0.f);
        if (orig < NROI) {
            const float4 rr = *(const float4*)(rois + (size_t)orig * 4);
            const float4 ll = *(const float4*)(locs + (size_t)orig * (NCLS * 4) + cc * 4);
            float h = rr.z - rr.x, w = rr.w - rr.y;
            float cy = rr.x + 0.5f * h, cx = rr.y + 0.5f * w;
            float dy = ll.x * 0.1f, dx = ll.y * 0.1f;
            float dh = ll.z * 0.2f, dw = ll.w * 0.2f;
            float ncy = dy * h + cy;
            float ncx = dx * w + cx;
            float nh = expf(dh) * h;
            float nw = expf(dw) * w;
            float b0 = ncy - 0.5f * nh;
            float b1 = ncx - 0.5f * nw;
            float b2 = ncy + 0.5f * nh;
            float b3 = ncx + 0.5f * nw;
            bb.x = fminf(fmaxf(b0, 0.0f), oh);
            bb.y = fminf(fmaxf(b1, 0.0f), ow);
            bb.z = fminf(fmaxf(b2, 0.0f), oh);
            bb.w = fminf(fmaxf(b3, 0.0f), ow);
        }
        sbox[c * NPAD + slot] = bb;
    }
    __syncthreads();
    if (t == 0) Vc[c] = vcount;
}

// -------- kernel 2: suppression bitmask, LDS-staged + unrolled --------
// Wave owns word jb (columns j0..j0+63). Boxes staged in LDS once
// (coalesced, single vmcnt drain); row loop reads via ds_read (lgkmcnt) so
// mask stores (vmcnt) never serialize it. Rows 8-at-a-time per wave.
// Covers exactly rows r < min(V, j0+64); ballot bits at columns >= V are
// provably masked by k_scan's validm / consume-before-write ordering.
__global__ void __launch_bounds__(512) k_mask(const float4* __restrict__ sbox,
                                              const int* __restrict__ Vc,
                                              u64* __restrict__ mask) {
#pragma clang fp contract(off)
    int c = blockIdx.y;
    int V = Vc[c];
    int jb = blockIdx.x;
    int j0 = jb << 6;
    if (j0 >= V) return;
    int tid = threadIdx.x;
    int lane = tid & 63;
    int wv = tid >> 6;                       // 8 waves
    int rmax = min(V, j0 + 64);
    int smax = j0 + 64;                      // covers rows [0,rmax) and cols [j0,j0+64)

    __shared__ float4 lb[NPAD];
    const float4* sb = sbox + c * NPAD;
    for (int i = tid; i < smax; i += 512) lb[i] = sb[i];
    __syncthreads();

    int j = j0 + lane;
    float4 cb = lb[j];
    float areaC = (cb.z - cb.x) * (cb.w - cb.y);
    u64* mrow = mask + (size_t)(c * NPAD) * 32 + jb;

    for (int r0 = wv * 8; r0 < rmax; r0 += 64) {
#pragma unroll
        for (int k = 0; k < 8; ++k) {
            int r = r0 + k;
            bool act = r < rmax;
            float4 rb = lb[act ? r : 0];
            float areaR = (rb.z - rb.x) * (rb.w - rb.y);
            float ty = fmaxf(rb.x, cb.x);
            float tx = fmaxf(rb.y, cb.y);
            float by = fminf(rb.z, cb.z);
            float bx = fminf(rb.w, cb.w);
            float ih = fmaxf(by - ty, 0.0f);
            float iw = fmaxf(bx - tx, 0.0f);
            float inter = ih * iw;
            float denom = ((areaR + areaC) - inter) + 1e-12f;
            float iou = inter / denom;
            u64 bits = __ballot((j > r) && (iou > 0.3f));
            if (act && lane == 0) mrow[(size_t)r * 32] = bits;
        }
    }
}

// -------- kernel 3: tiled greedy scan + direct output scatter --------
__global__ void __launch_bounds__(64, 1) k_scan(const int* __restrict__ sidx,
                                                const float* __restrict__ sprob,
                                                const float4* __restrict__ sbox,
                                                const int* __restrict__ Vc,
                                                const u64* __restrict__ mask,
                                                float* __restrict__ out) {
    int c = blockIdx.x;
    int V = Vc[c];
    if (V <= 0) return;
    int lane = threadIdx.x;
    int w = lane & 31;
    const u64* mbase = mask + (size_t)c * NPAD * 32;

    int ntiles = (V + 63) >> 6;
    u64 remv = 0;
    u64 d = mbase[(size_t)lane * 32 + 0];   // diag block, tile 0

    for (int t = 0; t < ntiles; ++t) {
        u64 dn = 0;
        if (t + 1 < ntiles)
            dn = mbase[(size_t)(64 * (t + 1) + lane) * 32 + (t + 1)];

        // this tile's per-row payload (issued early, independent of decisions)
        int r = 64 * t + lane;
        bool act = r < V;
        int ri = act ? r : 0;
        int orig = sidx[c * NPAD + ri];
        float pr = sprob[c * NPAD + ri];
        float4 bb = sbox[c * NPAD + ri];

        // unconditional row-word loads for this tile (independent, batched)
        u64 pf[64];
        const u64* rp = mbase + (size_t)(64 * t) * 32 + w;
#pragma unroll
        for (int j = 0; j < 64; ++j) pf[j] = rp[(size_t)j * 32];

        // register-only greedy resolution on the diagonal block
        u64 rv = __shfl(remv, t);            // word t, uniform
        int rem = V - 64 * t;
        u64 validm = (rem >= 64) ? ~0ULL : ((1ULL << rem) - 1ULL);
        u64 cur = (~rv) & validm;
        u64 kept = 0;
        while (cur) {
            int j = __ffsll((u64)cur) - 1;
            kept |= 1ULL << j;
            cur &= ~__shfl(d, j);
            cur &= ~(1ULL << j);
        }

        // branchless masked accumulate (garbage words provably masked:
        // word w is consumed at tile w, strictly before any tile > w writes it)
        u64 acc = 0;
#pragma unroll
        for (int j = 0; j < 64; ++j) {
            u64 sel = 0ULL - ((kept >> j) & 1ULL);
            acc |= pf[j] & sel;
        }
        remv |= acc;

        // scatter kept rows directly to the output (non-kept are prefilled)
        if (act && ((kept >> lane) & 1ULL)) {
            size_t to = (size_t)c * NROI + orig;
            float* o5 = out + to * 5;
            o5[0] = bb.x; o5[1] = bb.y; o5[2] = bb.z; o5[3] = bb.w; o5[4] = pr;
            out[(size_t)5 * NTOT + to] = 1.0f;
        }
        d = dn;
    }
}

extern "C" void kernel_launch(void* const* d_in, const int* in_sizes, int n_in,
                              void* d_out, int out_size, void* d_ws, size_t ws_size,
                              hipStream_t stream) {
    const float* rois   = (const float*)d_in[0];
    const float* locs   = (const float*)d_in[1];
    const float* scores = (const float*)d_in[2];
    const float* scale  = (const float*)d_in[3];
    float* out = (float*)d_out;

    char* ws = (char*)d_ws;
    int*    sidx  = (int*)(ws + OFF_SIDX);
    float*  sprob = (float*)(ws + OFF_SPROB);
    float4* sbox  = (float4*)(ws + OFF_SBOX);
    int*    Vc    = (int*)(ws + OFF_VC);
    u64*    mask  = (u64*)(ws + OFF_MASK);

    hipLaunchKernelGGL(k_sort, dim3(NFG), dim3(256), 0, stream,
                       rois, locs, scores, scale, sidx, sprob, sbox, Vc, out);
    hipLaunchKernelGGL(k_mask, dim3(32, NFG), dim3(512), 0, stream,
                       sbox, Vc, mask);
    hipLaunchKernelGGL(k_scan, dim3(NFG), dim3(64), 0, stream,
                       sidx, sprob, sbox, Vc, mask, out);
}

// Round 7
// 87.647 us; speedup vs baseline: 1.0176x; 1.0176x over previous
//
#include <hip/hip_runtime.h>
#include <math.h>

#define NROI 2000
#define NCLS 21
#define NFG  20
#define NPAD 2048
#define NTOT (NFG * NROI)

// ---- workspace layout (bytes) ----
#define OFF_PROBS   0u          // float  [NFG*NROI]            160000
#define OFF_SIDX    160000u     // int    [NFG*NPAD]            163840
#define OFF_SPROB   323840u     // float  [NFG*NPAD]            163840
#define OFF_SBOX    487680u     // float4 [NFG*NPAD]            655360
#define OFF_VC      1143040u    // int    [NFG] (padded)           256
#define OFF_MASK    1143296u    // u64    [NFG*NPAD*32]       10485760
// total ~11.6 MB

typedef unsigned long long u64;

// -------- kernel 1: wide softmax, one ROI per thread --------
// Each ROI's 21-way softmax computed ONCE (vs 20x when fused into the
// per-class sort blocks — that was R5's 46us regression). Writes fg-class
// probs class-major for coalesced reads in k_sort.
__global__ void k_prob(const float* __restrict__ scores,
                       float* __restrict__ probs) {
#pragma clang fp contract(off)
    int n = blockIdx.x * blockDim.x + threadIdx.x;
    if (n >= NROI) return;
    float s[NCLS];
    float m = -__builtin_inff();
#pragma unroll
    for (int k = 0; k < NCLS; ++k) {
        s[k] = scores[n * NCLS + k];
        m = fmaxf(m, s[k]);
    }
    float sum = 0.0f;
#pragma unroll
    for (int k = 0; k < NCLS; ++k) sum += expf(s[k] - m);
#pragma unroll
    for (int c = 0; c < NFG; ++c)
        probs[c * NROI + n] = expf(s[c + 1] - m) / sum;
}

// -------- kernel 2: sort + box decode + output prefill, one block/class ----
#define CSW(A,B,UP) { u64 lo_ = x[A] < x[B] ? x[A] : x[B]; \
                      u64 hi_ = x[A] < x[B] ? x[B] : x[A]; \
                      x[A] = (UP) ? lo_ : hi_; x[B] = (UP) ? hi_ : lo_; }

__global__ void __launch_bounds__(256) k_sort(const float* __restrict__ rois,
                                              const float* __restrict__ locs,
                                              const float* __restrict__ probs,
                                              const float* __restrict__ scale,
                                              int* __restrict__ sidx,
                                              float* __restrict__ sprob,
                                              float4* __restrict__ sbox,
                                              int* __restrict__ Vc,
                                              float* __restrict__ out) {
#pragma clang fp contract(off)
    int c = blockIdx.x;            // fg class index 0..19
    int cc = c + 1;                // loc class index (skip background)
    int t = threadIdx.x;
    __shared__ u64 a[NPAD];
    __shared__ int vcount;
    if (t == 0) vcount = 0;

    // ---- build keys from precomputed probs (coalesced) ----
    u64 x[8];
    int cnt = 0;
#pragma unroll
    for (int i = 0; i < 8; ++i) {
        int e = 8 * t + i;
        unsigned int u;
        if (e < NROI) {
            float pr = probs[c * NROI + e];
            bool valid = pr > 0.05f;
            cnt += valid ? 1 : 0;
            float key = valid ? pr : -__builtin_inff();
            u = __float_as_uint(key);
        } else {
            u = __float_as_uint(-__builtin_inff());
        }
        u ^= (u >> 31) ? 0xFFFFFFFFu : 0x80000000u;   // order-preserving map
        x[i] = ((u64)(~u) << 32) | (unsigned int)e;   // asc == desc-prob, ties idx asc
    }
    __syncthreads();                 // vcount init visible
    if (cnt) atomicAdd(&vcount, cnt);

    // ---- prefill this class's output slice (keep-independent) ----
    {
        float4 z4 = make_float4(0.f, 0.f, 0.f, 0.f);
        float4* o5v = (float4*)out + (size_t)c * (NROI * 5 / 4);  // 10000 floats = 2500 f4
        for (int i = t; i < NROI * 5 / 4; i += 256) o5v[i] = z4;
        float lc = (float)c;
        for (int i = t; i < NROI; i += 256) {
            out[(size_t)5 * NTOT + c * NROI + i] = 0.0f;   // keep
            out[(size_t)6 * NTOT + c * NROI + i] = lc;     // labels
        }
    }

    // ---- bitonic network (256 thr x 8 elems) ----
    // k=2: up = (i&2)==0
    CSW(0,1,true)  CSW(2,3,false) CSW(4,5,true)  CSW(6,7,false)
    // k=4: up = (i&4)==0
    CSW(0,2,true)  CSW(1,3,true)  CSW(4,6,false) CSW(5,7,false)
    CSW(0,1,true)  CSW(2,3,true)  CSW(4,5,false) CSW(6,7,false)
    // k=8: up = (t&1)==0
    {
        bool up = (t & 1) == 0;
        CSW(0,4,up) CSW(1,5,up) CSW(2,6,up) CSW(3,7,up)
        CSW(0,2,up) CSW(1,3,up) CSW(4,6,up) CSW(5,7,up)
        CSW(0,1,up) CSW(2,3,up) CSW(4,5,up) CSW(6,7,up)
    }
    // k >= 16
    for (unsigned int k = 16; k <= NPAD; k <<= 1) {
        bool up = (((unsigned int)(8 * t)) & k) == 0;
        for (unsigned int j = k >> 1; j >= 8; j >>= 1) {
            if (j >= 512) {                       // cross-wave: LDS
                __syncthreads();
#pragma unroll
                for (int i = 0; i < 8; ++i) a[8 * t + i] = x[i];
                __syncthreads();
                bool lower = ((t & (j >> 3)) == 0);
                bool takeMin = (up == lower);
#pragma unroll
                for (int i = 0; i < 8; ++i) {
                    u64 y = a[(8 * t + i) ^ j];
                    u64 mn = x[i] < y ? x[i] : y;
                    u64 mx = x[i] < y ? y : x[i];
                    x[i] = takeMin ? mn : mx;
                }
            } else {                              // wave-local: shfl_xor
                int lm = (int)(j >> 3);
                bool lower = ((t & lm) == 0);
                bool takeMin = (up == lower);
#pragma unroll
                for (int i = 0; i < 8; ++i) {
                    u64 y = __shfl_xor(x[i], lm, 64);
                    u64 mn = x[i] < y ? x[i] : y;
                    u64 mx = x[i] < y ? y : x[i];
                    x[i] = takeMin ? mn : mx;
                }
            }
        }
        // j = 4,2,1 in registers
        CSW(0,4,up) CSW(1,5,up) CSW(2,6,up) CSW(3,7,up)
        CSW(0,2,up) CSW(1,3,up) CSW(4,6,up) CSW(5,7,up)
        CSW(0,1,up) CSW(2,3,up) CSW(4,5,up) CSW(6,7,up)
    }

    // ---- emit sorted slots: idx, prob (bit-exact from key), decoded box ----
    float sc = scale[0];
    float oh = 600.0f / sc, ow = 800.0f / sc;
#pragma unroll
    for (int i = 0; i < 8; ++i) {
        int slot = 8 * t + i;
        u64 p = x[i];
        int orig = (int)(p & 0xFFFFFFFFu);
        sidx[c * NPAD + slot] = orig;
        // invert the order-preserving map to recover prob bits exactly
        unsigned int m_ = ~(unsigned int)(p >> 32);
        unsigned int b_ = (m_ & 0x80000000u) ? (m_ ^ 0x80000000u) : ~m_;
        sprob[c * NPAD + slot] = __uint_as_float(b_);

        float4 bb = make_float4(0.f, 0.f, 0.f, 0.f);
        if (orig < NROI) {
            const float4 rr = *(const float4*)(rois + (size_t)orig * 4);
            const float4 ll = *(const float4*)(locs + (size_t)orig * (NCLS * 4) + cc * 4);
            float h = rr.z - rr.x, w = rr.w - rr.y;
            float cy = rr.x + 0.5f * h, cx = rr.y + 0.5f * w;
            float dy = ll.x * 0.1f, dx = ll.y * 0.1f;
            float dh = ll.z * 0.2f, dw = ll.w * 0.2f;
            float ncy = dy * h + cy;
            float ncx = dx * w + cx;
            float nh = expf(dh) * h;
            float nw = expf(dw) * w;
            float b0 = ncy - 0.5f * nh;
            float b1 = ncx - 0.5f * nw;
            float b2 = ncy + 0.5f * nh;
            float b3 = ncx + 0.5f * nw;
            bb.x = fminf(fmaxf(b0, 0.0f), oh);
            bb.y = fminf(fmaxf(b1, 0.0f), ow);
            bb.z = fminf(fmaxf(b2, 0.0f), oh);
            bb.w = fminf(fmaxf(b3, 0.0f), ow);
        }
        sbox[c * NPAD + slot] = bb;
    }
    __syncthreads();
    if (t == 0) Vc[c] = vcount;
}

// -------- kernel 3: suppression bitmask, LDS-staged + unrolled --------
// Wave owns word jb (columns j0..j0+63). Boxes staged in LDS once
// (coalesced, single vmcnt drain); row loop reads via ds_read (lgkmcnt) so
// mask stores (vmcnt) never serialize it. Rows 8-at-a-time per wave.
// Covers exactly rows r < min(V, j0+64); ballot bits at columns >= V are
// provably masked by k_scan's validm / consume-before-write ordering.
__global__ void __launch_bounds__(512) k_mask(const float4* __restrict__ sbox,
                                              const int* __restrict__ Vc,
                                              u64* __restrict__ mask) {
#pragma clang fp contract(off)
    int c = blockIdx.y;
    int V = Vc[c];
    int jb = blockIdx.x;
    int j0 = jb << 6;
    if (j0 >= V) return;
    int tid = threadIdx.x;
    int lane = tid & 63;
    int wv = tid >> 6;                       // 8 waves
    int rmax = min(V, j0 + 64);
    int smax = j0 + 64;                      // covers rows [0,rmax) and cols [j0,j0+64)

    __shared__ float4 lb[NPAD];
    const float4* sb = sbox + c * NPAD;
    for (int i = tid; i < smax; i += 512) lb[i] = sb[i];
    __syncthreads();

    int j = j0 + lane;
    float4 cb = lb[j];
    float areaC = (cb.z - cb.x) * (cb.w - cb.y);
    u64* mrow = mask + (size_t)(c * NPAD) * 32 + jb;

    for (int r0 = wv * 8; r0 < rmax; r0 += 64) {
#pragma unroll
        for (int k = 0; k < 8; ++k) {
            int r = r0 + k;
            bool act = r < rmax;
            float4 rb = lb[act ? r : 0];
            float areaR = (rb.z - rb.x) * (rb.w - rb.y);
            float ty = fmaxf(rb.x, cb.x);
            float tx = fmaxf(rb.y, cb.y);
            float by = fminf(rb.z, cb.z);
            float bx = fminf(rb.w, cb.w);
            float ih = fmaxf(by - ty, 0.0f);
            float iw = fmaxf(bx - tx, 0.0f);
            float inter = ih * iw;
            float denom = ((areaR + areaC) - inter) + 1e-12f;
            float iou = inter / denom;
            u64 bits = __ballot((j > r) && (iou > 0.3f));
            if (act && lane == 0) mrow[(size_t)r * 32] = bits;
        }
    }
}

// -------- kernel 4: tiled greedy scan + direct output scatter --------
__global__ void __launch_bounds__(64, 1) k_scan(const int* __restrict__ sidx,
                                                const float* __restrict__ sprob,
                                                const float4* __restrict__ sbox,
                                                const int* __restrict__ Vc,
                                                const u64* __restrict__ mask,
                                                float* __restrict__ out) {
    int c = blockIdx.x;
    int V = Vc[c];
    if (V <= 0) return;
    int lane = threadIdx.x;
    int w = lane & 31;
    const u64* mbase = mask + (size_t)c * NPAD * 32;

    int ntiles = (V + 63) >> 6;
    u64 remv = 0;
    u64 d = mbase[(size_t)lane * 32 + 0];   // diag block, tile 0

    for (int t = 0; t < ntiles; ++t) {
        u64 dn = 0;
        if (t + 1 < ntiles)
            dn = mbase[(size_t)(64 * (t + 1) + lane) * 32 + (t + 1)];

        // this tile's per-row payload (issued early, independent of decisions)
        int r = 64 * t + lane;
        bool act = r < V;
        int ri = act ? r : 0;
        int orig = sidx[c * NPAD + ri];
        float pr = sprob[c * NPAD + ri];
        float4 bb = sbox[c * NPAD + ri];

        // unconditional row-word loads for this tile (independent, batched)
        u64 pf[64];
        const u64* rp = mbase + (size_t)(64 * t) * 32 + w;
#pragma unroll
        for (int j = 0; j < 64; ++j) pf[j] = rp[(size_t)j * 32];

        // register-only greedy resolution on the diagonal block
        u64 rv = __shfl(remv, t);            // word t, uniform
        int rem = V - 64 * t;
        u64 validm = (rem >= 64) ? ~0ULL : ((1ULL << rem) - 1ULL);
        u64 cur = (~rv) & validm;
        u64 kept = 0;
        while (cur) {
            int j = __ffsll((u64)cur) - 1;
            kept |= 1ULL << j;
            cur &= ~__shfl(d, j);
            cur &= ~(1ULL << j);
        }

        // branchless masked accumulate (garbage words provably masked:
        // word w is consumed at tile w, strictly before any tile > w writes it)
        u64 acc = 0;
#pragma unroll
        for (int j = 0; j < 64; ++j) {
            u64 sel = 0ULL - ((kept >> j) & 1ULL);
            acc |= pf[j] & sel;
        }
        remv |= acc;

        // scatter kept rows directly to the output (non-kept are prefilled)
        if (act && ((kept >> lane) & 1ULL)) {
            size_t to = (size_t)c * NROI + orig;
            float* o5 = out + to * 5;
            o5[0] = bb.x; o5[1] = bb.y; o5[2] = bb.z; o5[3] = bb.w; o5[4] = pr;
            out[(size_t)5 * NTOT + to] = 1.0f;
        }
        d = dn;
    }
}

extern "C" void kernel_launch(void* const* d_in, const int* in_sizes, int n_in,
                              void* d_out, int out_size, void* d_ws, size_t ws_size,
                              hipStream_t stream) {
    const float* rois   = (const float*)d_in[0];
    const float* locs   = (const float*)d_in[1];
    const float* scores = (const float*)d_in[2];
    const float* scale  = (const float*)d_in[3];
    float* out = (float*)d_out;

    char* ws = (char*)d_ws;
    float*  probs = (float*)(ws + OFF_PROBS);
    int*    sidx  = (int*)(ws + OFF_SIDX);
    float*  sprob = (float*)(ws + OFF_SPROB);
    float4* sbox  = (float4*)(ws + OFF_SBOX);
    int*    Vc    = (int*)(ws + OFF_VC);
    u64*    mask  = (u64*)(ws + OFF_MASK);

    hipLaunchKernelGGL(k_prob, dim3(32), dim3(64), 0, stream,
                       scores, probs);
    hipLaunchKernelGGL(k_sort, dim3(NFG), dim3(256), 0, stream,
                       rois, locs, probs, scale, sidx, sprob, sbox, Vc, out);
    hipLaunchKernelGGL(k_mask, dim3(32, NFG), dim3(512), 0, stream,
                       sbox, Vc, mask);
    hipLaunchKernelGGL(k_scan, dim3(NFG), dim3(64), 0, stream,
                       sidx, sprob, sbox, Vc, mask, out);
}